// Round 7
// baseline (1250.513 us; speedup 1.0000x reference)
//
#include <hip/hip_runtime.h>
#include <math.h>

#define N_ROWS 262144
#define KCODES 512
#define DIM 64
#define BLOCK 256              // 4 waves x 32 rows = 128 rows/block
#define ROWS_PER_BLOCK 128
#define NSUB 32                // 32 substeps of 16 codes
#define SUBS_PER_STAGE 4       // KTILE=64 codes per LDS stage
#define NSTAGES (NSUB / SUBS_PER_STAGE)
#define STAGE_USHORTS (SUBS_PER_STAGE * 6 * 64 * 8)   // 12288 ushorts = 24 KB

// Fragment-major B layout (built by vq_prep):
//   pe[((st16*6 + f)*64 + lane) * 8 + j]
// st16 = 16-code substep, f = plane*2 + khalf (h0,h1,m0,m1,l0,l1),
// lane = q*16 + c holds code st16*16+c, k = khalf*32 + q*8 + j.
// Staged through LDS unchanged: linear 16B/thread copies (coalesced global,
// conflict-free LDS), substep reads at lane*16B (2 lanes/bank = free).

typedef __attribute__((ext_vector_type(8))) short short8;   // 8 bf16 = 4 VGPRs
typedef __attribute__((ext_vector_type(4))) float f4;       // MFMA acc / 16B vec

// Output layout (flat fp32, reference return order):
static const size_t OFF_LOSS = 0;
static const size_t OFF_Q    = 1;
static const size_t OFF_PERP = 1 + (size_t)N_ROWS * DIM;
static const size_t OFF_ENC  = OFF_PERP + 1;
static const size_t OFF_IDX  = OFF_ENC + (size_t)N_ROWS * KCODES;

__device__ __forceinline__ unsigned short bf16rne(float f) {
    unsigned int u = __float_as_uint(f);
    u = (u + 0x7fffu + ((u >> 16) & 1u)) >> 16;
    return (unsigned short)u;
}
__device__ __forceinline__ float bf16tof(unsigned short h) {
    return __uint_as_float(((unsigned int)h) << 16);
}

// Kernel 1: L2-normalize embedding rows, 3-way bf16 split, fragment-major layout.
__global__ __launch_bounds__(64) void vq_prep(const float* __restrict__ emb,
                                              unsigned short* __restrict__ pe,
                                              float* __restrict__ out_loss,
                                              float* __restrict__ out_perp) {
    int k = blockIdx.x;    // code
    int d = threadIdx.x;   // dim
    float v = emb[k * DIM + d];
    float s = v * v;
    #pragma unroll
    for (int off = 32; off > 0; off >>= 1) s += __shfl_xor(s, off, 64);
    float vn = v / fmaxf(sqrtf(s), 1e-12f);
    unsigned short h = bf16rne(vn);
    float r = vn - bf16tof(h);
    unsigned short m = bf16rne(r);
    r = r - bf16tof(m);
    unsigned short l = bf16rne(r);
    // code k -> substep st, col c; dim d -> khalf ss, quad qq, elem j
    int st = k >> 4, cc = k & 15;
    int ss = d >> 5, qq = (d >> 3) & 3, j = d & 7;
    int ln = qq * 16 + cc;
    pe[((size_t)(st * 6 + 0 + ss) * 64 + ln) * 8 + j] = h;   // f = 0,1
    pe[((size_t)(st * 6 + 2 + ss) * 64 + ln) * 8 + j] = m;   // f = 2,3
    pe[((size_t)(st * 6 + 4 + ss) * 64 + ln) * 8 + j] = l;   // f = 4,5
    if (k == 0 && d == 0) { *out_loss = 0.0f; *out_perp = 1.0f; }
}

#define MFMA(A, B, C) C = __builtin_amdgcn_mfma_f32_16x16x32_bf16(A, B, C, 0, 0, 0)

// Kernel 2: R1 structure (best measured): LDS-staged B shared by 4 waves,
// barriers, ALL stores in epilogue (grid-level block-generation pipelining
// overlaps them with other blocks' compute). This round's lever: occupancy.
// 24 KB LDS + launch_bounds(256,6) -> 6 blocks/CU = 24 waves/CU (was 12).
__global__ __launch_bounds__(BLOCK, 6) void vq_main(const float* __restrict__ x,
                                                    const int* __restrict__ labels,
                                                    const float* __restrict__ emb,
                                                    const unsigned short* __restrict__ pe,
                                                    float* __restrict__ out_loss,
                                                    float* __restrict__ out_q,
                                                    float* __restrict__ out_enc,
                                                    float* __restrict__ out_idx) {
    const int tid   = threadIdx.x;
    const int lane  = tid & 63;
    const int q     = lane >> 4;       // quad 0..3
    const int c     = lane & 15;
    const int wbase = blockIdx.x * ROWS_PER_BLOCK + (tid >> 6) * 32;  // wave's 32 rows

    __shared__ __align__(16) unsigned short sE[STAGE_USHORTS];  // 24 KB

    // ---- A fragments + per-row inverse norms + 3-way bf16 split.
    float inv_nx[2];
    short8 Ah[2][2], Am[2][2], Al[2][2];
    #pragma unroll
    for (int t = 0; t < 2; ++t) {
        float xv[16];
        const float* xp = x + (size_t)(wbase + t * 16 + c) * DIM + q * 8;
        #pragma unroll
        for (int s = 0; s < 2; ++s) {
            float4 lo = *(const float4*)(xp + s * 32);
            float4 hi = *(const float4*)(xp + s * 32 + 4);
            xv[s * 8 + 0] = lo.x; xv[s * 8 + 1] = lo.y;
            xv[s * 8 + 2] = lo.z; xv[s * 8 + 3] = lo.w;
            xv[s * 8 + 4] = hi.x; xv[s * 8 + 5] = hi.y;
            xv[s * 8 + 6] = hi.z; xv[s * 8 + 7] = hi.w;
        }
        float s2 = 0.f;
        #pragma unroll
        for (int j = 0; j < 16; ++j) s2 = fmaf(xv[j], xv[j], s2);
        s2 += __shfl_xor(s2, 16, 64);
        s2 += __shfl_xor(s2, 32, 64);
        inv_nx[t] = 1.0f / fmaxf(sqrtf(s2), 1e-12f);
        // 3-way bf16 split (no normalization: argmax-invariant).
        #pragma unroll
        for (int s = 0; s < 2; ++s)
            #pragma unroll
            for (int j = 0; j < 8; ++j) {
                float v = xv[s * 8 + j];
                unsigned short h = bf16rne(v);
                float r = v - bf16tof(h);
                unsigned short m = bf16rne(r);
                r = r - bf16tof(m);
                unsigned short l = bf16rne(r);
                Ah[t][s][j] = (short)h;
                Am[t][s][j] = (short)m;
                Al[t][s][j] = (short)l;
            }
    }

    // labels for this lane's 8 C-rows (rows t*16 + q*4 + r)
    int   lbl[2][4];
    float best[2][4], pick[2][4];
    int   bidx[2][4];
    #pragma unroll
    for (int t = 0; t < 2; ++t)
        #pragma unroll
        for (int r = 0; r < 4; ++r) {
            lbl[t][r]  = labels[wbase + t * 16 + q * 4 + r];
            best[t][r] = -3.4e38f;
            bidx[t][r] = 0;
            pick[t][r] = 0.f;
        }

    for (int stg = 0; stg < NSTAGES; ++stg) {
        __syncthreads();
        // Stage 24 KB (4 substeps x 6 frags x 1KB): 1536 16B-chunks, 6/thread.
        // Linear copy: coalesced global reads, conflict-free LDS writes.
        {
            const unsigned short* src = pe + (size_t)stg * STAGE_USHORTS;
            #pragma unroll
            for (int i = 0; i < 6; ++i) {
                int ch = tid + i * BLOCK;
                *(f4*)&sE[ch * 8] = *(const f4*)(src + ch * 8);
            }
        }
        __syncthreads();

        #pragma unroll
        for (int sub = 0; sub < SUBS_PER_STAGE; ++sub) {
            // B frags at lane*16B within each 1KB fragment block (bank-free).
            const unsigned short* bp = &sE[((sub * 6) * 64 + lane) * 8];
            short8 Bh0 = *(const short8*)(bp);             // f=0
            short8 Bh1 = *(const short8*)(bp + 512);       // f=1
            short8 Bm0 = *(const short8*)(bp + 1024);      // f=2
            short8 Bm1 = *(const short8*)(bp + 1536);      // f=3
            short8 Bl0 = *(const short8*)(bp + 2048);      // f=4
            short8 Bl1 = *(const short8*)(bp + 2560);      // f=5

            f4 acc0 = {0.f, 0.f, 0.f, 0.f};
            f4 acc1 = {0.f, 0.f, 0.f, 0.f};
            // 6 split-products x 2 K-steps, both M-tiles (B reused 2x).
            MFMA(Ah[0][0], Bh0, acc0);  MFMA(Ah[1][0], Bh0, acc1);
            MFMA(Ah[0][1], Bh1, acc0);  MFMA(Ah[1][1], Bh1, acc1);
            MFMA(Ah[0][0], Bm0, acc0);  MFMA(Ah[1][0], Bm0, acc1);
            MFMA(Ah[0][1], Bm1, acc0);  MFMA(Ah[1][1], Bm1, acc1);
            MFMA(Am[0][0], Bh0, acc0);  MFMA(Am[1][0], Bh0, acc1);
            MFMA(Am[0][1], Bh1, acc0);  MFMA(Am[1][1], Bh1, acc1);
            MFMA(Ah[0][0], Bl0, acc0);  MFMA(Ah[1][0], Bl0, acc1);
            MFMA(Ah[0][1], Bl1, acc0);  MFMA(Ah[1][1], Bl1, acc1);
            MFMA(Al[0][0], Bh0, acc0);  MFMA(Al[1][0], Bh0, acc1);
            MFMA(Al[0][1], Bh1, acc0);  MFMA(Al[1][1], Bh1, acc1);
            MFMA(Am[0][0], Bm0, acc0);  MFMA(Am[1][0], Bm0, acc1);
            MFMA(Am[0][1], Bm1, acc0);  MFMA(Am[1][1], Bm1, acc1);

            const int code = (stg * SUBS_PER_STAGE + sub) * 16 + c;
            #pragma unroll
            for (int r = 0; r < 4; ++r) {
                float d0 = acc0[r];
                if (d0 > best[0][r]) { best[0][r] = d0; bidx[0][r] = code; }
                if (code == lbl[0][r]) pick[0][r] = d0;
                float d1 = acc1[r];
                if (d1 > best[1][r]) { best[1][r] = d1; bidx[1][r] = code; }
                if (code == lbl[1][r]) pick[1][r] = d1;
            }
        }
    }

    // Cross-lane argmax reduce within 16-lane col groups (tie -> smaller idx
    // = first max, matching jnp.argmax); pick is one-hot so sum-reduce.
    // Butterfly leaves results on ALL lanes of each group.
    #pragma unroll
    for (int t = 0; t < 2; ++t)
        #pragma unroll
        for (int r = 0; r < 4; ++r) {
            float b = best[t][r]; int i = bidx[t][r]; float p = pick[t][r];
            #pragma unroll
            for (int m = 1; m < 16; m <<= 1) {
                float ob = __shfl_xor(b, m, 64);
                int   oi = __shfl_xor(i, m, 64);
                p += __shfl_xor(p, m, 64);
                if (ob > b || (ob == b && oi < i)) { b = ob; i = oi; }
            }
            bidx[t][r] = i; pick[t][r] = p;
        }

    // one-hot rows: full-line coalesced 16B nt stores, 1.0 embedded.
    // Row r32 = t*16 + q*4 + r; its bidx lives in col-group q -> one shfl.
    {
        const int col0 = lane * 4, col1 = 256 + lane * 4;
        #pragma unroll
        for (int r32 = 0; r32 < 32; ++r32) {
            int bi = __shfl(bidx[r32 >> 4][r32 & 3], ((r32 >> 2) & 3) * 16, 64);
            float* base = out_enc + (size_t)(wbase + r32) * KCODES;
            f4 v0 = { bi == col0     ? 1.f : 0.f,
                      bi == col0 + 1 ? 1.f : 0.f,
                      bi == col0 + 2 ? 1.f : 0.f,
                      bi == col0 + 3 ? 1.f : 0.f };
            __builtin_nontemporal_store(v0, (f4*)(base + col0));
            f4 v1 = { bi == col1     ? 1.f : 0.f,
                      bi == col1 + 1 ? 1.f : 0.f,
                      bi == col1 + 2 ? 1.f : 0.f,
                      bi == col1 + 3 ? 1.f : 0.f };
            __builtin_nontemporal_store(v1, (f4*)(base + col1));
        }
    }

    // idx: owner lanes (c==0) write their quad's 8 rows.
    if (c == 0) {
        #pragma unroll
        for (int t = 0; t < 2; ++t)
            #pragma unroll
            for (int r = 0; r < 4; ++r) {
                int row = wbase + t * 16 + q * 4 + r;
                out_idx[row] = (float)bidx[t][r];
            }
    }

    // quantized = raw emb row at argmax. Lane's quad owns rows q*4+r; bidx is
    // lane-local after the reduce. Element c -> 16 lanes cover the 64-f row.
    #pragma unroll
    for (int t = 0; t < 2; ++t)
        #pragma unroll
        for (int r = 0; r < 4; ++r) {
            int row = wbase + t * 16 + q * 4 + r;
            f4 v = ((const f4*)(emb + (size_t)bidx[t][r] * DIM))[c];
            __builtin_nontemporal_store(v, ((f4*)(out_q + (size_t)row * DIM)) + c);
        }

    // loss = mean(1 - dist[row, label_row]); dist = split-dot * inv_norm.
    // Each quad's 16 lanes duplicate its 8 rows -> scale by 1/16.
    float lv = 0.f;
    #pragma unroll
    for (int t = 0; t < 2; ++t)
        #pragma unroll
        for (int r = 0; r < 4; ++r) {
            float invv = __shfl(inv_nx[t], q * 4 + r, 64);  // row t*16+q*4+r
            lv += (1.0f - pick[t][r] * invv);
        }
    lv *= 1.0f / ((float)N_ROWS * 16.0f);
    #pragma unroll
    for (int m = 1; m < 64; m <<= 1) lv += __shfl_xor(lv, m, 64);
    if (lane == 0) atomicAdd(out_loss, lv);
}

extern "C" void kernel_launch(void* const* d_in, const int* in_sizes, int n_in,
                              void* d_out, int out_size, void* d_ws, size_t ws_size,
                              hipStream_t stream) {
    const float* x      = (const float*)d_in[0];
    const int*   labels = (const int*)d_in[1];
    const float* emb    = (const float*)d_in[2];
    float* out = (float*)d_out;
    unsigned short* pe = (unsigned short*)d_ws;   // 192 KB fragment-major planes

    hipLaunchKernelGGL(vq_prep, dim3(KCODES), dim3(64), 0, stream,
                       emb, pe, out + OFF_LOSS, out + OFF_PERP);
    hipLaunchKernelGGL(vq_main, dim3(N_ROWS / ROWS_PER_BLOCK), dim3(BLOCK), 0, stream,
                       x, labels, emb, pe,
                       out + OFF_LOSS, out + OFF_Q, out + OFF_ENC, out + OFF_IDX);
}

// Round 8
// 892.354 us; speedup vs baseline: 1.4014x; 1.4014x over previous
//
#include <hip/hip_runtime.h>
#include <math.h>

#define N_ROWS 262144
#define KCODES 512
#define DIM 64
#define BLOCK 256              // 4 waves x 32 rows = 128 rows/block
#define ROWS_PER_BLOCK 128
#define NSUB 32                // 32 substeps of 16 codes
#define SUBS_PER_STAGE 4       // KTILE=64 codes per LDS stage
#define NSTAGES (NSUB / SUBS_PER_STAGE)
#define STAGE_USHORTS (SUBS_PER_STAGE * 6 * 64 * 8)   // 12288 ushorts = 24 KB

// Fragment-major B layout (built by vq_prep):
//   pe[((st16*6 + f)*64 + lane) * 8 + j]
// st16 = 16-code substep, f = plane*2 + khalf (h0,h1,m0,m1,l0,l1),
// lane = q*16 + c holds code st16*16+c, k = khalf*32 + q*8 + j.

typedef __attribute__((ext_vector_type(8))) short short8;   // 8 bf16 = 4 VGPRs
typedef __attribute__((ext_vector_type(4))) float f4;       // MFMA acc / 16B vec
typedef __attribute__((ext_vector_type(2))) float f2;       // 8B aligned stores

// Output layout (flat fp32, reference return order):
// NOTE alignment: OFF_Q = 1 (q rows at byte 4 mod 16), OFF_ENC = 16777218
// (enc rows at byte 8 mod 16). float4 stores to these are MISALIGNED and
// split into 2 transactions each. enc => float2 (8B-aligned ok), q => dword.
static const size_t OFF_LOSS = 0;
static const size_t OFF_Q    = 1;
static const size_t OFF_PERP = 1 + (size_t)N_ROWS * DIM;
static const size_t OFF_ENC  = OFF_PERP + 1;
static const size_t OFF_IDX  = OFF_ENC + (size_t)N_ROWS * KCODES;

__device__ __forceinline__ unsigned short bf16rne(float f) {
    unsigned int u = __float_as_uint(f);
    u = (u + 0x7fffu + ((u >> 16) & 1u)) >> 16;
    return (unsigned short)u;
}
__device__ __forceinline__ float bf16tof(unsigned short h) {
    return __uint_as_float(((unsigned int)h) << 16);
}

// Kernel 1: L2-normalize embedding rows, 3-way bf16 split, fragment-major layout.
__global__ __launch_bounds__(64) void vq_prep(const float* __restrict__ emb,
                                              unsigned short* __restrict__ pe,
                                              float* __restrict__ out_loss,
                                              float* __restrict__ out_perp) {
    int k = blockIdx.x;    // code
    int d = threadIdx.x;   // dim
    float v = emb[k * DIM + d];
    float s = v * v;
    #pragma unroll
    for (int off = 32; off > 0; off >>= 1) s += __shfl_xor(s, off, 64);
    float vn = v / fmaxf(sqrtf(s), 1e-12f);
    unsigned short h = bf16rne(vn);
    float r = vn - bf16tof(h);
    unsigned short m = bf16rne(r);
    r = r - bf16tof(m);
    unsigned short l = bf16rne(r);
    // code k -> substep st, col c; dim d -> khalf ss, quad qq, elem j
    int st = k >> 4, cc = k & 15;
    int ss = d >> 5, qq = (d >> 3) & 3, j = d & 7;
    int ln = qq * 16 + cc;
    pe[((size_t)(st * 6 + 0 + ss) * 64 + ln) * 8 + j] = h;   // f = 0,1
    pe[((size_t)(st * 6 + 2 + ss) * 64 + ln) * 8 + j] = m;   // f = 2,3
    pe[((size_t)(st * 6 + 4 + ss) * 64 + ln) * 8 + j] = l;   // f = 4,5
    if (k == 0 && d == 0) { *out_loss = 0.0f; *out_perp = 1.0f; }
}

#define MFMA(A, B, C) C = __builtin_amdgcn_mfma_f32_16x16x32_bf16(A, B, C, 0, 0, 0)

// Kernel 2: best-known structure (R1): LDS-staged B shared by 4 waves,
// barriers, stores in epilogue. launch_bounds(256,3): R7 proved (256,6)
// spills everything (VGPR=40, 2.7GB scratch traffic). This round's single
// variable: ALIGNED stores (enc f2, q dword) instead of misaligned f4.
__global__ __launch_bounds__(BLOCK, 3) void vq_main(const float* __restrict__ x,
                                                    const int* __restrict__ labels,
                                                    const float* __restrict__ emb,
                                                    const unsigned short* __restrict__ pe,
                                                    float* __restrict__ out_loss,
                                                    float* __restrict__ out_q,
                                                    float* __restrict__ out_enc,
                                                    float* __restrict__ out_idx) {
    const int tid   = threadIdx.x;
    const int lane  = tid & 63;
    const int q     = lane >> 4;       // quad 0..3
    const int c     = lane & 15;
    const int wbase = blockIdx.x * ROWS_PER_BLOCK + (tid >> 6) * 32;  // wave's 32 rows

    __shared__ __align__(16) unsigned short sE[STAGE_USHORTS];  // 24 KB

    // ---- A fragments + per-row inverse norms + 3-way bf16 split.
    float inv_nx[2];
    short8 Ah[2][2], Am[2][2], Al[2][2];
    #pragma unroll
    for (int t = 0; t < 2; ++t) {
        float xv[16];
        const float* xp = x + (size_t)(wbase + t * 16 + c) * DIM + q * 8;
        #pragma unroll
        for (int s = 0; s < 2; ++s) {
            float4 lo = *(const float4*)(xp + s * 32);
            float4 hi = *(const float4*)(xp + s * 32 + 4);
            xv[s * 8 + 0] = lo.x; xv[s * 8 + 1] = lo.y;
            xv[s * 8 + 2] = lo.z; xv[s * 8 + 3] = lo.w;
            xv[s * 8 + 4] = hi.x; xv[s * 8 + 5] = hi.y;
            xv[s * 8 + 6] = hi.z; xv[s * 8 + 7] = hi.w;
        }
        float s2 = 0.f;
        #pragma unroll
        for (int j = 0; j < 16; ++j) s2 = fmaf(xv[j], xv[j], s2);
        s2 += __shfl_xor(s2, 16, 64);
        s2 += __shfl_xor(s2, 32, 64);
        inv_nx[t] = 1.0f / fmaxf(sqrtf(s2), 1e-12f);
        // 3-way bf16 split (no normalization: argmax-invariant).
        #pragma unroll
        for (int s = 0; s < 2; ++s)
            #pragma unroll
            for (int j = 0; j < 8; ++j) {
                float v = xv[s * 8 + j];
                unsigned short h = bf16rne(v);
                float r = v - bf16tof(h);
                unsigned short m = bf16rne(r);
                r = r - bf16tof(m);
                unsigned short l = bf16rne(r);
                Ah[t][s][j] = (short)h;
                Am[t][s][j] = (short)m;
                Al[t][s][j] = (short)l;
            }
    }

    // labels for this lane's 8 C-rows (rows t*16 + q*4 + r)
    int   lbl[2][4];
    float best[2][4], pick[2][4];
    int   bidx[2][4];
    #pragma unroll
    for (int t = 0; t < 2; ++t)
        #pragma unroll
        for (int r = 0; r < 4; ++r) {
            lbl[t][r]  = labels[wbase + t * 16 + q * 4 + r];
            best[t][r] = -3.4e38f;
            bidx[t][r] = 0;
            pick[t][r] = 0.f;
        }

    for (int stg = 0; stg < NSTAGES; ++stg) {
        __syncthreads();
        // Stage 24 KB (4 substeps x 6 frags x 1KB): 1536 16B-chunks, 6/thread.
        // Linear copy: coalesced global reads, conflict-free LDS writes.
        {
            const unsigned short* src = pe + (size_t)stg * STAGE_USHORTS;
            #pragma unroll
            for (int i = 0; i < 6; ++i) {
                int ch = tid + i * BLOCK;
                *(f4*)&sE[ch * 8] = *(const f4*)(src + ch * 8);
            }
        }
        __syncthreads();

        #pragma unroll
        for (int sub = 0; sub < SUBS_PER_STAGE; ++sub) {
            // B frags at lane*16B within each 1KB fragment block (bank-free).
            const unsigned short* bp = &sE[((sub * 6) * 64 + lane) * 8];
            short8 Bh0 = *(const short8*)(bp);             // f=0
            short8 Bh1 = *(const short8*)(bp + 512);       // f=1
            short8 Bm0 = *(const short8*)(bp + 1024);      // f=2
            short8 Bm1 = *(const short8*)(bp + 1536);      // f=3
            short8 Bl0 = *(const short8*)(bp + 2048);      // f=4
            short8 Bl1 = *(const short8*)(bp + 2560);      // f=5

            f4 acc0 = {0.f, 0.f, 0.f, 0.f};
            f4 acc1 = {0.f, 0.f, 0.f, 0.f};
            // 6 split-products x 2 K-steps, both M-tiles (B reused 2x).
            MFMA(Ah[0][0], Bh0, acc0);  MFMA(Ah[1][0], Bh0, acc1);
            MFMA(Ah[0][1], Bh1, acc0);  MFMA(Ah[1][1], Bh1, acc1);
            MFMA(Ah[0][0], Bm0, acc0);  MFMA(Ah[1][0], Bm0, acc1);
            MFMA(Ah[0][1], Bm1, acc0);  MFMA(Ah[1][1], Bm1, acc1);
            MFMA(Am[0][0], Bh0, acc0);  MFMA(Am[1][0], Bh0, acc1);
            MFMA(Am[0][1], Bh1, acc0);  MFMA(Am[1][1], Bh1, acc1);
            MFMA(Ah[0][0], Bl0, acc0);  MFMA(Ah[1][0], Bl0, acc1);
            MFMA(Ah[0][1], Bl1, acc0);  MFMA(Ah[1][1], Bl1, acc1);
            MFMA(Al[0][0], Bh0, acc0);  MFMA(Al[1][0], Bh0, acc1);
            MFMA(Al[0][1], Bh1, acc0);  MFMA(Al[1][1], Bh1, acc1);
            MFMA(Am[0][0], Bm0, acc0);  MFMA(Am[1][0], Bm0, acc1);
            MFMA(Am[0][1], Bm1, acc0);  MFMA(Am[1][1], Bm1, acc1);

            const int code = (stg * SUBS_PER_STAGE + sub) * 16 + c;
            #pragma unroll
            for (int r = 0; r < 4; ++r) {
                float d0 = acc0[r];
                if (d0 > best[0][r]) { best[0][r] = d0; bidx[0][r] = code; }
                if (code == lbl[0][r]) pick[0][r] = d0;
                float d1 = acc1[r];
                if (d1 > best[1][r]) { best[1][r] = d1; bidx[1][r] = code; }
                if (code == lbl[1][r]) pick[1][r] = d1;
            }
        }
    }

    // Cross-lane argmax reduce within 16-lane col groups (tie -> smaller idx
    // = first max, matching jnp.argmax); pick is one-hot so sum-reduce.
    // Butterfly leaves results on ALL lanes of each group.
    #pragma unroll
    for (int t = 0; t < 2; ++t)
        #pragma unroll
        for (int r = 0; r < 4; ++r) {
            float b = best[t][r]; int i = bidx[t][r]; float p = pick[t][r];
            #pragma unroll
            for (int m = 1; m < 16; m <<= 1) {
                float ob = __shfl_xor(b, m, 64);
                int   oi = __shfl_xor(i, m, 64);
                p += __shfl_xor(p, m, 64);
                if (ob > b || (ob == b && oi < i)) { b = ob; i = oi; }
            }
            bidx[t][r] = i; pick[t][r] = p;
        }

    // one-hot rows: 1.0 embedded, ALIGNED float2 stores (row base is byte
    // 8 mod 16 -> every f2 at base+2k floats is 8B-aligned; f4 would split).
    // Row r32 = t*16 + q'*4 + r; its bidx lives in col-group q' -> one shfl.
    {
        #pragma unroll
        for (int r32 = 0; r32 < 32; ++r32) {
            int bi = __shfl(bidx[r32 >> 4][r32 & 3], ((r32 >> 2) & 3) * 16, 64);
            float* base = out_enc + (size_t)(wbase + r32) * KCODES + lane * 8;
            #pragma unroll
            for (int p = 0; p < 4; ++p) {
                int c0 = lane * 8 + p * 2;
                f2 v = { bi == c0 ? 1.f : 0.f, bi == c0 + 1 ? 1.f : 0.f };
                __builtin_nontemporal_store(v, (f2*)(base + p * 2));
            }
        }
    }

    // idx: owner lanes (c==0) write their quad's 8 rows.
    if (c == 0) {
        #pragma unroll
        for (int t = 0; t < 2; ++t)
            #pragma unroll
            for (int r = 0; r < 4; ++r) {
                int row = wbase + t * 16 + q * 4 + r;
                out_idx[row] = (float)bidx[t][r];
            }
    }

    // quantized = raw emb row at argmax. q rows are byte 4 mod 16 -> dword
    // stores (always aligned); emb reads stay 16B-aligned f4.
    #pragma unroll
    for (int t = 0; t < 2; ++t)
        #pragma unroll
        for (int r = 0; r < 4; ++r) {
            int row = wbase + t * 16 + q * 4 + r;
            f4 v = ((const f4*)(emb + (size_t)bidx[t][r] * DIM))[c];
            float* qb = out_q + (size_t)row * DIM + c * 4;
            __builtin_nontemporal_store(v.x, qb);
            __builtin_nontemporal_store(v.y, qb + 1);
            __builtin_nontemporal_store(v.z, qb + 2);
            __builtin_nontemporal_store(v.w, qb + 3);
        }

    // loss = mean(1 - dist[row, label_row]); dist = split-dot * inv_norm.
    // Each quad's 16 lanes duplicate its 8 rows -> scale by 1/16.
    float lv = 0.f;
    #pragma unroll
    for (int t = 0; t < 2; ++t)
        #pragma unroll
        for (int r = 0; r < 4; ++r) {
            float invv = __shfl(inv_nx[t], q * 4 + r, 64);  // row t*16+q*4+r
            lv += (1.0f - pick[t][r] * invv);
        }
    lv *= 1.0f / ((float)N_ROWS * 16.0f);
    #pragma unroll
    for (int m = 1; m < 64; m <<= 1) lv += __shfl_xor(lv, m, 64);
    if (lane == 0) atomicAdd(out_loss, lv);
}

extern "C" void kernel_launch(void* const* d_in, const int* in_sizes, int n_in,
                              void* d_out, int out_size, void* d_ws, size_t ws_size,
                              hipStream_t stream) {
    const float* x      = (const float*)d_in[0];
    const int*   labels = (const int*)d_in[1];
    const float* emb    = (const float*)d_in[2];
    float* out = (float*)d_out;
    unsigned short* pe = (unsigned short*)d_ws;   // 192 KB fragment-major planes

    hipLaunchKernelGGL(vq_prep, dim3(KCODES), dim3(64), 0, stream,
                       emb, pe, out + OFF_LOSS, out + OFF_PERP);
    hipLaunchKernelGGL(vq_main, dim3(N_ROWS / ROWS_PER_BLOCK), dim3(BLOCK), 0, stream,
                       x, labels, emb, pe,
                       out + OFF_LOSS, out + OFF_Q, out + OFF_ENC, out + OFF_IDX);
}

// Round 9
// 867.689 us; speedup vs baseline: 1.4412x; 1.0284x over previous
//
#include <hip/hip_runtime.h>
#include <math.h>

#define N_ROWS 262144
#define KCODES 512
#define DIM 64
#define BLOCK 256              // 4 waves x 32 rows = 128 rows/block
#define ROWS_PER_BLOCK 128
#define NSUB 32                // 32 substeps of 16 codes
#define SUBS_PER_STAGE 4       // KTILE=64 codes per LDS stage
#define NSTAGES (NSUB / SUBS_PER_STAGE)
#define STAGE_USHORTS (SUBS_PER_STAGE * 6 * 64 * 8)   // 12288 ushorts = 24 KB

// Fragment-major B layout (built by vq_prep):
//   pe[((st16*6 + f)*64 + lane) * 8 + j]
// st16 = 16-code substep, f = plane*2 + khalf (h0,h1,m0,m1,l0,l1),
// lane = q*16 + c holds code st16*16+c, k = khalf*32 + q*8 + j.

typedef __attribute__((ext_vector_type(8))) short short8;   // 8 bf16 = 4 VGPRs
typedef __attribute__((ext_vector_type(4))) float f4;       // MFMA acc / 16B vec

// Output layout (flat fp32, reference return order):
static const size_t OFF_LOSS = 0;
static const size_t OFF_Q    = 1;
static const size_t OFF_PERP = 1 + (size_t)N_ROWS * DIM;
static const size_t OFF_ENC  = OFF_PERP + 1;
static const size_t OFF_IDX  = OFF_ENC + (size_t)N_ROWS * KCODES;

__device__ __forceinline__ unsigned short bf16rne(float f) {
    unsigned int u = __float_as_uint(f);
    u = (u + 0x7fffu + ((u >> 16) & 1u)) >> 16;
    return (unsigned short)u;
}
__device__ __forceinline__ float bf16tof(unsigned short h) {
    return __uint_as_float(((unsigned int)h) << 16);
}

// Kernel 1: L2-normalize embedding rows, 3-way bf16 split, fragment-major layout.
__global__ __launch_bounds__(64) void vq_prep(const float* __restrict__ emb,
                                              unsigned short* __restrict__ pe,
                                              float* __restrict__ out_loss,
                                              float* __restrict__ out_perp) {
    int k = blockIdx.x;    // code
    int d = threadIdx.x;   // dim
    float v = emb[k * DIM + d];
    float s = v * v;
    #pragma unroll
    for (int off = 32; off > 0; off >>= 1) s += __shfl_xor(s, off, 64);
    float vn = v / fmaxf(sqrtf(s), 1e-12f);
    unsigned short h = bf16rne(vn);
    float r = vn - bf16tof(h);
    unsigned short m = bf16rne(r);
    r = r - bf16tof(m);
    unsigned short l = bf16rne(r);
    // code k -> substep st, col c; dim d -> khalf ss, quad qq, elem j
    int st = k >> 4, cc = k & 15;
    int ss = d >> 5, qq = (d >> 3) & 3, j = d & 7;
    int ln = qq * 16 + cc;
    pe[((size_t)(st * 6 + 0 + ss) * 64 + ln) * 8 + j] = h;   // f = 0,1
    pe[((size_t)(st * 6 + 2 + ss) * 64 + ln) * 8 + j] = m;   // f = 2,3
    pe[((size_t)(st * 6 + 4 + ss) * 64 + ln) * 8 + j] = l;   // f = 4,5
    if (k == 0 && d == 0) { *out_loss = 0.0f; *out_perp = 1.0f; }
}

#define MFMA(A, B, C) C = __builtin_amdgcn_mfma_f32_16x16x32_bf16(A, B, C, 0, 0, 0)

// Kernel 2: compute + argmax + patches only. The 537MB enc-zero stream is
// done by hipMemsetAsync BEFORE this kernel (runtime fill = proven 6.3TB/s
// at 10% occupancy; stores issued from latency-stalled compute waves never
// reach that pace). vq_main writes just: 1.0f patches (1MB), q (67MB, f4),
// idx (1MB), loss. R8 measured VGPR=80 -> bound 4 (cap 128) is spill-safe.
__global__ __launch_bounds__(BLOCK, 4) void vq_main(const float* __restrict__ x,
                                                    const int* __restrict__ labels,
                                                    const float* __restrict__ emb,
                                                    const unsigned short* __restrict__ pe,
                                                    float* __restrict__ out_loss,
                                                    float* __restrict__ out_q,
                                                    float* __restrict__ out_enc,
                                                    float* __restrict__ out_idx) {
    const int tid   = threadIdx.x;
    const int lane  = tid & 63;
    const int q     = lane >> 4;       // quad 0..3
    const int c     = lane & 15;
    const int wbase = blockIdx.x * ROWS_PER_BLOCK + (tid >> 6) * 32;  // wave's 32 rows

    __shared__ __align__(16) unsigned short sE[STAGE_USHORTS];  // 24 KB

    // ---- A fragments + per-row inverse norms + 3-way bf16 split.
    float inv_nx[2];
    short8 Ah[2][2], Am[2][2], Al[2][2];
    #pragma unroll
    for (int t = 0; t < 2; ++t) {
        float xv[16];
        const float* xp = x + (size_t)(wbase + t * 16 + c) * DIM + q * 8;
        #pragma unroll
        for (int s = 0; s < 2; ++s) {
            float4 lo = *(const float4*)(xp + s * 32);
            float4 hi = *(const float4*)(xp + s * 32 + 4);
            xv[s * 8 + 0] = lo.x; xv[s * 8 + 1] = lo.y;
            xv[s * 8 + 2] = lo.z; xv[s * 8 + 3] = lo.w;
            xv[s * 8 + 4] = hi.x; xv[s * 8 + 5] = hi.y;
            xv[s * 8 + 6] = hi.z; xv[s * 8 + 7] = hi.w;
        }
        float s2 = 0.f;
        #pragma unroll
        for (int j = 0; j < 16; ++j) s2 = fmaf(xv[j], xv[j], s2);
        s2 += __shfl_xor(s2, 16, 64);
        s2 += __shfl_xor(s2, 32, 64);
        inv_nx[t] = 1.0f / fmaxf(sqrtf(s2), 1e-12f);
        // 3-way bf16 split (no normalization: argmax-invariant).
        #pragma unroll
        for (int s = 0; s < 2; ++s)
            #pragma unroll
            for (int j = 0; j < 8; ++j) {
                float v = xv[s * 8 + j];
                unsigned short h = bf16rne(v);
                float r = v - bf16tof(h);
                unsigned short m = bf16rne(r);
                r = r - bf16tof(m);
                unsigned short l = bf16rne(r);
                Ah[t][s][j] = (short)h;
                Am[t][s][j] = (short)m;
                Al[t][s][j] = (short)l;
            }
    }

    // labels for this lane's 8 C-rows (rows t*16 + q*4 + r)
    int   lbl[2][4];
    float best[2][4], pick[2][4];
    int   bidx[2][4];
    #pragma unroll
    for (int t = 0; t < 2; ++t)
        #pragma unroll
        for (int r = 0; r < 4; ++r) {
            lbl[t][r]  = labels[wbase + t * 16 + q * 4 + r];
            best[t][r] = -3.4e38f;
            bidx[t][r] = 0;
            pick[t][r] = 0.f;
        }

    for (int stg = 0; stg < NSTAGES; ++stg) {
        __syncthreads();
        // Stage 24 KB (4 substeps x 6 frags x 1KB): 1536 16B-chunks, 6/thread.
        // Linear copy: coalesced global reads, conflict-free LDS writes.
        {
            const unsigned short* src = pe + (size_t)stg * STAGE_USHORTS;
            #pragma unroll
            for (int i = 0; i < 6; ++i) {
                int ch = tid + i * BLOCK;
                *(f4*)&sE[ch * 8] = *(const f4*)(src + ch * 8);
            }
        }
        __syncthreads();

        #pragma unroll
        for (int sub = 0; sub < SUBS_PER_STAGE; ++sub) {
            // B frags at lane*16B within each 1KB fragment block (bank-free).
            const unsigned short* bp = &sE[((sub * 6) * 64 + lane) * 8];
            short8 Bh0 = *(const short8*)(bp);             // f=0
            short8 Bh1 = *(const short8*)(bp + 512);       // f=1
            short8 Bm0 = *(const short8*)(bp + 1024);      // f=2
            short8 Bm1 = *(const short8*)(bp + 1536);      // f=3
            short8 Bl0 = *(const short8*)(bp + 2048);      // f=4
            short8 Bl1 = *(const short8*)(bp + 2560);      // f=5

            f4 acc0 = {0.f, 0.f, 0.f, 0.f};
            f4 acc1 = {0.f, 0.f, 0.f, 0.f};
            // 6 split-products x 2 K-steps, both M-tiles (B reused 2x).
            MFMA(Ah[0][0], Bh0, acc0);  MFMA(Ah[1][0], Bh0, acc1);
            MFMA(Ah[0][1], Bh1, acc0);  MFMA(Ah[1][1], Bh1, acc1);
            MFMA(Ah[0][0], Bm0, acc0);  MFMA(Ah[1][0], Bm0, acc1);
            MFMA(Ah[0][1], Bm1, acc0);  MFMA(Ah[1][1], Bm1, acc1);
            MFMA(Am[0][0], Bh0, acc0);  MFMA(Am[1][0], Bh0, acc1);
            MFMA(Am[0][1], Bh1, acc0);  MFMA(Am[1][1], Bh1, acc1);
            MFMA(Ah[0][0], Bl0, acc0);  MFMA(Ah[1][0], Bl0, acc1);
            MFMA(Ah[0][1], Bl1, acc0);  MFMA(Ah[1][1], Bl1, acc1);
            MFMA(Al[0][0], Bh0, acc0);  MFMA(Al[1][0], Bh0, acc1);
            MFMA(Al[0][1], Bh1, acc0);  MFMA(Al[1][1], Bh1, acc1);
            MFMA(Am[0][0], Bm0, acc0);  MFMA(Am[1][0], Bm0, acc1);
            MFMA(Am[0][1], Bm1, acc0);  MFMA(Am[1][1], Bm1, acc1);

            const int code = (stg * SUBS_PER_STAGE + sub) * 16 + c;
            #pragma unroll
            for (int r = 0; r < 4; ++r) {
                float d0 = acc0[r];
                if (d0 > best[0][r]) { best[0][r] = d0; bidx[0][r] = code; }
                if (code == lbl[0][r]) pick[0][r] = d0;
                float d1 = acc1[r];
                if (d1 > best[1][r]) { best[1][r] = d1; bidx[1][r] = code; }
                if (code == lbl[1][r]) pick[1][r] = d1;
            }
        }
    }

    // Cross-lane argmax reduce within 16-lane col groups (tie -> smaller idx
    // = first max, matching jnp.argmax); pick is one-hot so sum-reduce.
    // Butterfly leaves results on ALL lanes of each group.
    #pragma unroll
    for (int t = 0; t < 2; ++t)
        #pragma unroll
        for (int r = 0; r < 4; ++r) {
            float b = best[t][r]; int i = bidx[t][r]; float p = pick[t][r];
            #pragma unroll
            for (int m = 1; m < 16; m <<= 1) {
                float ob = __shfl_xor(b, m, 64);
                int   oi = __shfl_xor(i, m, 64);
                p += __shfl_xor(p, m, 64);
                if (ob > b || (ob == b && oi < i)) { b = ob; i = oi; }
            }
            bidx[t][r] = i; pick[t][r] = p;
        }

    // enc: buffer was zeroed by hipMemsetAsync before this kernel; write only
    // the 1.0 at the argmax column + idx. Owner lanes (c==0), 8 rows each.
    if (c == 0) {
        #pragma unroll
        for (int t = 0; t < 2; ++t)
            #pragma unroll
            for (int r = 0; r < 4; ++r) {
                int row = wbase + t * 16 + q * 4 + r;
                out_enc[(size_t)row * KCODES + bidx[t][r]] = 1.0f;
                out_idx[row] = (float)bidx[t][r];
            }
    }

    // quantized = raw emb row at argmax. Lane's quad owns rows q*4+r; bidx is
    // lane-local after the reduce. f4 (misaligned-split, R1-proven; NOT
    // scalar nt: R8 measured 8x write amplification on scalar nt stores).
    #pragma unroll
    for (int t = 0; t < 2; ++t)
        #pragma unroll
        for (int r = 0; r < 4; ++r) {
            int row = wbase + t * 16 + q * 4 + r;
            f4 v = ((const f4*)(emb + (size_t)bidx[t][r] * DIM))[c];
            __builtin_nontemporal_store(v, ((f4*)(out_q + (size_t)row * DIM)) + c);
        }

    // loss = mean(1 - dist[row, label_row]); dist = split-dot * inv_norm.
    // Each quad's 16 lanes duplicate its 8 rows -> scale by 1/16.
    float lv = 0.f;
    #pragma unroll
    for (int t = 0; t < 2; ++t)
        #pragma unroll
        for (int r = 0; r < 4; ++r) {
            float invv = __shfl(inv_nx[t], q * 4 + r, 64);  // row t*16+q*4+r
            lv += (1.0f - pick[t][r] * invv);
        }
    lv *= 1.0f / ((float)N_ROWS * 16.0f);
    #pragma unroll
    for (int m = 1; m < 64; m <<= 1) lv += __shfl_xor(lv, m, 64);
    if (lane == 0) atomicAdd(out_loss, lv);
}

extern "C" void kernel_launch(void* const* d_in, const int* in_sizes, int n_in,
                              void* d_out, int out_size, void* d_ws, size_t ws_size,
                              hipStream_t stream) {
    const float* x      = (const float*)d_in[0];
    const int*   labels = (const int*)d_in[1];
    const float* emb    = (const float*)d_in[2];
    float* out = (float*)d_out;
    unsigned short* pe = (unsigned short*)d_ws;   // 192 KB fragment-major planes

    hipLaunchKernelGGL(vq_prep, dim3(KCODES), dim3(64), 0, stream,
                       emb, pe, out + OFF_LOSS, out + OFF_PERP);
    // Zero the 537MB enc region via the runtime fill path (stream-ordered,
    // graph-capturable async memset; ~6.3TB/s). vq_main patches the 1.0s.
    hipMemsetAsync(out + OFF_ENC, 0, (size_t)N_ROWS * KCODES * sizeof(float),
                   stream);
    hipLaunchKernelGGL(vq_main, dim3(N_ROWS / ROWS_PER_BLOCK), dim3(BLOCK), 0, stream,
                       x, labels, emb, pe,
                       out + OFF_LOSS, out + OFF_Q, out + OFF_ENC, out + OFF_IDX);
}

// Round 10
// 711.308 us; speedup vs baseline: 1.7580x; 1.2198x over previous
//
#include <hip/hip_runtime.h>
#include <math.h>

#define N_ROWS 262144
#define KCODES 512
#define DIM 64
#define BLOCK 256              // 4 waves x 32 rows = 128 rows/block
#define ROWS_PER_BLOCK 128
#define KTILE 64               // codes staged per LDS tile
#define NSTAGES (KCODES / KTILE)
#define LDS_ROW 72             // 64 + 8 pad bf16 elems = 144 B stride (bank-balanced)
#define PLANE_STRIDE (KTILE * LDS_ROW)   // ushorts

typedef __attribute__((ext_vector_type(8))) short short8;   // 8 bf16 = 4 VGPRs
typedef __attribute__((ext_vector_type(4))) float f4;       // MFMA acc / 16B vec

// Output layout (flat fp32, reference return order):
static const size_t OFF_LOSS = 0;
static const size_t OFF_Q    = 1;
static const size_t OFF_PERP = 1 + (size_t)N_ROWS * DIM;
static const size_t OFF_ENC  = OFF_PERP + 1;
static const size_t OFF_IDX  = OFF_ENC + (size_t)N_ROWS * KCODES;

__device__ __forceinline__ unsigned short bf16rne(float f) {
    unsigned int u = __float_as_uint(f);
    u = (u + 0x7fffu + ((u >> 16) & 1u)) >> 16;
    return (unsigned short)u;
}
__device__ __forceinline__ float bf16tof(unsigned short h) {
    return __uint_as_float(((unsigned int)h) << 16);
}

// Kernel 1: L2-normalize embedding rows, 3-way bf16 split into ws planes.
__global__ __launch_bounds__(64) void vq_prep(const float* __restrict__ emb,
                                              unsigned short* __restrict__ ph,
                                              unsigned short* __restrict__ pm,
                                              unsigned short* __restrict__ pl,
                                              float* __restrict__ out_loss,
                                              float* __restrict__ out_perp) {
    int k = blockIdx.x;
    int d = threadIdx.x;
    float v = emb[k * DIM + d];
    float s = v * v;
    #pragma unroll
    for (int off = 32; off > 0; off >>= 1) s += __shfl_xor(s, off, 64);
    float vn = v / fmaxf(sqrtf(s), 1e-12f);
    unsigned short h = bf16rne(vn);
    float r = vn - bf16tof(h);
    unsigned short m = bf16rne(r);
    r = r - bf16tof(m);
    unsigned short l = bf16rne(r);
    ph[k * DIM + d] = h;
    pm[k * DIM + d] = m;
    pl[k * DIM + d] = l;
    if (k == 0 && d == 0) { *out_loss = 0.0f; *out_perp = 1.0f; }
}

#define MFMA(A, B, C) C = __builtin_amdgcn_mfma_f32_16x16x32_bf16(A, B, C, 0, 0, 0)

// Kernel 2: R1 structure (best measured, 703us total): padded-LDS staged B,
// barriers, inline f4 epilogue stores (R9 proved stores are ~free inline;
// memset was a net loss). This round's levers against the ~80% stall:
//  (a) occupancy 3->4 blocks/CU (cap 128 vs ~90 needed -> no spill risk),
//  (b) accumulator ILP: 12-deep MFMA dep chains split into 2x6 by K-half.
__global__ __launch_bounds__(BLOCK, 4) void vq_main(const float* __restrict__ x,
                                                    const int* __restrict__ labels,
                                                    const float* __restrict__ emb,
                                                    const unsigned short* __restrict__ ph,
                                                    const unsigned short* __restrict__ pm,
                                                    const unsigned short* __restrict__ pl,
                                                    float* __restrict__ out_loss,
                                                    float* __restrict__ out_q,
                                                    float* __restrict__ out_enc,
                                                    float* __restrict__ out_idx) {
    const int tid   = threadIdx.x;
    const int lane  = tid & 63;
    const int q     = lane >> 4;       // quad 0..3
    const int c     = lane & 15;
    const int wbase = blockIdx.x * ROWS_PER_BLOCK + (tid >> 6) * 32;  // wave's 32 rows

    __shared__ __align__(16) unsigned short sE[3 * PLANE_STRIDE];  // ~27.6 KB

    // ---- A fragments + per-row inverse norms + 3-way bf16 split.
    float inv_nx[2];
    short8 Ah[2][2], Am[2][2], Al[2][2];
    #pragma unroll
    for (int t = 0; t < 2; ++t) {
        float xv[16];
        const float* xp = x + (size_t)(wbase + t * 16 + c) * DIM + q * 8;
        #pragma unroll
        for (int s = 0; s < 2; ++s) {
            float4 lo = *(const float4*)(xp + s * 32);
            float4 hi = *(const float4*)(xp + s * 32 + 4);
            xv[s * 8 + 0] = lo.x; xv[s * 8 + 1] = lo.y;
            xv[s * 8 + 2] = lo.z; xv[s * 8 + 3] = lo.w;
            xv[s * 8 + 4] = hi.x; xv[s * 8 + 5] = hi.y;
            xv[s * 8 + 6] = hi.z; xv[s * 8 + 7] = hi.w;
        }
        float s2 = 0.f;
        #pragma unroll
        for (int j = 0; j < 16; ++j) s2 = fmaf(xv[j], xv[j], s2);
        s2 += __shfl_xor(s2, 16, 64);
        s2 += __shfl_xor(s2, 32, 64);
        inv_nx[t] = 1.0f / fmaxf(sqrtf(s2), 1e-12f);
        // 3-way bf16 split (no normalization: argmax-invariant).
        #pragma unroll
        for (int s = 0; s < 2; ++s)
            #pragma unroll
            for (int j = 0; j < 8; ++j) {
                float v = xv[s * 8 + j];
                unsigned short h = bf16rne(v);
                float r = v - bf16tof(h);
                unsigned short m = bf16rne(r);
                r = r - bf16tof(m);
                unsigned short l = bf16rne(r);
                Ah[t][s][j] = (short)h;
                Am[t][s][j] = (short)m;
                Al[t][s][j] = (short)l;
            }
    }

    // labels for this lane's 8 C-rows (rows t*16 + q*4 + r)
    int   lbl[2][4];
    float best[2][4], pick[2][4];
    int   bidx[2][4];
    #pragma unroll
    for (int t = 0; t < 2; ++t)
        #pragma unroll
        for (int r = 0; r < 4; ++r) {
            lbl[t][r]  = labels[wbase + t * 16 + q * 4 + r];
            best[t][r] = -3.4e38f;
            bidx[t][r] = 0;
            pick[t][r] = 0.f;
        }

    for (int st = 0; st < NSTAGES; ++st) {
        __syncthreads();
        // Stage 3 planes of 64 codes: 512 16B-chunks/plane, 2 per thread.
        #pragma unroll
        for (int i = 0; i < 2; ++i) {
            int ch = tid + i * BLOCK;
            int code = ch >> 3, part = ch & 7;
            int dst = code * LDS_ROW + part * 8;
            int src = st * (KTILE * DIM) + ch * 8;
            *(float4*)&sE[dst]                    = *(const float4*)(ph + src);
            *(float4*)&sE[PLANE_STRIDE + dst]     = *(const float4*)(pm + src);
            *(float4*)&sE[2 * PLANE_STRIDE + dst] = *(const float4*)(pl + src);
        }
        __syncthreads();

        #pragma unroll 2
        for (int sub = 0; sub < KTILE / 16; ++sub) {
            // B frags: lane holds code (sub*16+c), k = s*32 + q*8 + j.
            const unsigned short* bp = &sE[(sub * 16 + c) * LDS_ROW + q * 8];
            short8 Bh0 = *(const short8*)(bp);
            short8 Bh1 = *(const short8*)(bp + 32);
            short8 Bm0 = *(const short8*)(bp + PLANE_STRIDE);
            short8 Bm1 = *(const short8*)(bp + PLANE_STRIDE + 32);
            short8 Bl0 = *(const short8*)(bp + 2 * PLANE_STRIDE);
            short8 Bl1 = *(const short8*)(bp + 2 * PLANE_STRIDE + 32);

            // 4 independent accumulator chains (M-tile x K-half), 6 MFMAs
            // each, instead of 2 chains of 12: halves dep-stall per substep.
            f4 a0a = {0.f, 0.f, 0.f, 0.f};
            f4 a0b = {0.f, 0.f, 0.f, 0.f};
            f4 a1a = {0.f, 0.f, 0.f, 0.f};
            f4 a1b = {0.f, 0.f, 0.f, 0.f};
            MFMA(Ah[0][0], Bh0, a0a);  MFMA(Ah[0][1], Bh1, a0b);
            MFMA(Ah[1][0], Bh0, a1a);  MFMA(Ah[1][1], Bh1, a1b);
            MFMA(Ah[0][0], Bm0, a0a);  MFMA(Ah[0][1], Bm1, a0b);
            MFMA(Ah[1][0], Bm0, a1a);  MFMA(Ah[1][1], Bm1, a1b);
            MFMA(Am[0][0], Bh0, a0a);  MFMA(Am[0][1], Bh1, a0b);
            MFMA(Am[1][0], Bh0, a1a);  MFMA(Am[1][1], Bh1, a1b);
            MFMA(Ah[0][0], Bl0, a0a);  MFMA(Ah[0][1], Bl1, a0b);
            MFMA(Ah[1][0], Bl0, a1a);  MFMA(Ah[1][1], Bl1, a1b);
            MFMA(Al[0][0], Bh0, a0a);  MFMA(Al[0][1], Bh1, a0b);
            MFMA(Al[1][0], Bh0, a1a);  MFMA(Al[1][1], Bh1, a1b);
            MFMA(Am[0][0], Bm0, a0a);  MFMA(Am[0][1], Bm1, a0b);
            MFMA(Am[1][0], Bm0, a1a);  MFMA(Am[1][1], Bm1, a1b);

            const int code = st * KTILE + sub * 16 + c;  // this lane's column
            #pragma unroll
            for (int r = 0; r < 4; ++r) {
                float d0 = a0a[r] + a0b[r];
                if (d0 > best[0][r]) { best[0][r] = d0; bidx[0][r] = code; }
                if (code == lbl[0][r]) pick[0][r] = d0;
                float d1 = a1a[r] + a1b[r];
                if (d1 > best[1][r]) { best[1][r] = d1; bidx[1][r] = code; }
                if (code == lbl[1][r]) pick[1][r] = d1;
            }
        }
    }

    // Cross-lane argmax reduce within 16-lane col groups (tie -> smaller idx
    // = first max, matching jnp.argmax); pick is one-hot so sum-reduce.
    // Butterfly leaves results on ALL lanes of each group.
    #pragma unroll
    for (int t = 0; t < 2; ++t)
        #pragma unroll
        for (int r = 0; r < 4; ++r) {
            float b = best[t][r]; int i = bidx[t][r]; float p = pick[t][r];
            #pragma unroll
            for (int m = 1; m < 16; m <<= 1) {
                float ob = __shfl_xor(b, m, 64);
                int   oi = __shfl_xor(i, m, 64);
                p += __shfl_xor(p, m, 64);
                if (ob > b || (ob == b && oi < i)) { b = ob; i = oi; }
            }
            bidx[t][r] = i; pick[t][r] = p;
        }

    // one-hot rows: full-line coalesced f4 nt stores, 1.0 embedded (R1-proven
    // fastest store scheme; inline stores are hidden under other blocks'
    // compute at grid level). Row r32's bidx lives in col-group (r32>>2)&3.
    {
        const int col0 = lane * 4, col1 = 256 + lane * 4;
        #pragma unroll
        for (int r32 = 0; r32 < 32; ++r32) {
            int bi = __shfl(bidx[r32 >> 4][r32 & 3], ((r32 >> 2) & 3) * 16, 64);
            float* base = out_enc + (size_t)(wbase + r32) * KCODES;
            f4 v0 = { bi == col0     ? 1.f : 0.f,
                      bi == col0 + 1 ? 1.f : 0.f,
                      bi == col0 + 2 ? 1.f : 0.f,
                      bi == col0 + 3 ? 1.f : 0.f };
            __builtin_nontemporal_store(v0, (f4*)(base + col0));
            f4 v1 = { bi == col1     ? 1.f : 0.f,
                      bi == col1 + 1 ? 1.f : 0.f,
                      bi == col1 + 2 ? 1.f : 0.f,
                      bi == col1 + 3 ? 1.f : 0.f };
            __builtin_nontemporal_store(v1, (f4*)(base + col1));
        }
    }

    // idx: owner lanes (c==0) write their quad's 8 rows.
    if (c == 0) {
        #pragma unroll
        for (int t = 0; t < 2; ++t)
            #pragma unroll
            for (int r = 0; r < 4; ++r) {
                int row = wbase + t * 16 + q * 4 + r;
                out_idx[row] = (float)bidx[t][r];
            }
    }

    // quantized = raw emb row at argmax; f4 stores (R1-proven; scalar nt
    // stores amplify writes 8x - R8).
    #pragma unroll
    for (int t = 0; t < 2; ++t)
        #pragma unroll
        for (int r = 0; r < 4; ++r) {
            int row = wbase + t * 16 + q * 4 + r;
            f4 v = ((const f4*)(emb + (size_t)bidx[t][r] * DIM))[c];
            __builtin_nontemporal_store(v, ((f4*)(out_q + (size_t)row * DIM)) + c);
        }

    // loss = mean(1 - dist[row, label_row]); dist = split-dot * inv_norm.
    // Each quad's 16 lanes duplicate its 8 rows -> scale by 1/16.
    float lv = 0.f;
    #pragma unroll
    for (int t = 0; t < 2; ++t)
        #pragma unroll
        for (int r = 0; r < 4; ++r) {
            float invv = __shfl(inv_nx[t], q * 4 + r, 64);  // row t*16+q*4+r
            lv += (1.0f - pick[t][r] * invv);
        }
    lv *= 1.0f / ((float)N_ROWS * 16.0f);
    #pragma unroll
    for (int m = 1; m < 64; m <<= 1) lv += __shfl_xor(lv, m, 64);
    if (lane == 0) atomicAdd(out_loss, lv);
}

extern "C" void kernel_launch(void* const* d_in, const int* in_sizes, int n_in,
                              void* d_out, int out_size, void* d_ws, size_t ws_size,
                              hipStream_t stream) {
    const float* x      = (const float*)d_in[0];
    const int*   labels = (const int*)d_in[1];
    const float* emb    = (const float*)d_in[2];
    float* out = (float*)d_out;
    unsigned short* ph = (unsigned short*)d_ws;              // 64 KB
    unsigned short* pm = ph + (size_t)KCODES * DIM;          // 64 KB
    unsigned short* pl = pm + (size_t)KCODES * DIM;          // 64 KB (192 KB total)

    hipLaunchKernelGGL(vq_prep, dim3(KCODES), dim3(64), 0, stream,
                       emb, ph, pm, pl, out + OFF_LOSS, out + OFF_PERP);
    hipLaunchKernelGGL(vq_main, dim3(N_ROWS / ROWS_PER_BLOCK), dim3(BLOCK), 0, stream,
                       x, labels, emb, ph, pm, pl,
                       out + OFF_LOSS, out + OFF_Q, out + OFF_ENC, out + OFF_IDX);
}